// Round 12
// baseline (465.613 us; speedup 1.0000x reference)
//
#include <hip/hip_runtime.h>
#include <hip/hip_fp16.h>

// EllipticGNN: 2-layer GCN + linear head, f32 compute.
// fp16 pre-scaled gather rows; pure-gather aggs; dense dot2 tail.
// R12: 32-row gemm1 tile (high occupancy), XCD-partitioned hist,
// 256-thread agg blocks.

constexpr int NN   = 100000;
constexpr int NE   = 1600000;
constexpr int FIN  = 165;
constexpr int HID  = 128;
constexpr int NPX  = NN / 8;            // 12500 nodes per XCD partition
constexpr int NCHUNK = 250;             // edge chunks per XCD
constexpr int EPC  = (NE + NCHUNK - 1) / NCHUNK;   // 6400 edges per chunk

typedef _Float16 h2v __attribute__((ext_vector_type(2)));

__device__ __forceinline__ float fdot2u(unsigned a, unsigned b, float c) {
#if __has_builtin(__builtin_amdgcn_fdot2)
    return __builtin_amdgcn_fdot2(__builtin_bit_cast(h2v, a),
                                  __builtin_bit_cast(h2v, b), c, false);
#else
    __half2 ah = __builtin_bit_cast(__half2, a);
    __half2 bh = __builtin_bit_cast(__half2, b);
    float2 af = __half22float2(ah), bf = __half22float2(bh);
    return fmaf(af.x, bf.x, fmaf(af.y, bf.y, c));
#endif
}

__global__ __launch_bounds__(256) void k_zero_counts(int* __restrict__ c) {
    int i = blockIdx.x * 256 + threadIdx.x;
    if (i < NN) c[i] = 0;
}

// XCD-partitioned histogram: block b (XCD b&7) counts only its dst range.
__global__ __launch_bounds__(256) void k_hist_x(const int* __restrict__ dst,
                                                int* __restrict__ c) {
    const int b  = blockIdx.x;
    const int lo = (b & 7) * NPX;
    const int hi = lo + NPX;
    const int q  = b >> 3;
    const int e0 = q * EPC;
    const int e1 = (e0 + EPC < NE) ? e0 + EPC : NE;
    for (int e = e0 + threadIdx.x; e < e1; e += 256) {
        int d = dst[e];
        if (d >= lo && d < hi) atomicAdd(&c[d], 1);
    }
}

// scanA + fused dinv: rowptr partial, block sums, dinv = rsqrt(c+1).
__global__ __launch_bounds__(256) void k_scanA(const int* __restrict__ c,
                                               int* __restrict__ rowptr,
                                               int* __restrict__ bsum,
                                               float* __restrict__ dinv) {
    __shared__ int s[256];
    int t = threadIdx.x;
    int i = blockIdx.x * 256 + t;
    int v = (i < NN) ? c[i] : 0;
    if (i < NN) dinv[i] = rsqrtf((float)v + 1.0f);   // +1 self-loop
    s[t] = v; __syncthreads();
    for (int off = 1; off < 256; off <<= 1) {
        int add = (t >= off) ? s[t - off] : 0;
        __syncthreads();
        s[t] += add;
        __syncthreads();
    }
    if (i < NN) rowptr[i] = s[t] - v;
    if (t == 255) bsum[blockIdx.x] = s[255];
}

__global__ __launch_bounds__(512) void k_scanB(int* __restrict__ bsum, int nb) {
    __shared__ int s[512];
    int t = threadIdx.x;
    int v = (t < nb) ? bsum[t] : 0;
    s[t] = v; __syncthreads();
    for (int off = 1; off < 512; off <<= 1) {
        int add = (t >= off) ? s[t - off] : 0;
        __syncthreads();
        s[t] += add;
        __syncthreads();
    }
    if (t < nb) bsum[t] = s[t] - v;
}

__global__ __launch_bounds__(256) void k_scanC(int* __restrict__ rowptr,
                                               const int* __restrict__ bsum,
                                               int* __restrict__ c) {
    int i = blockIdx.x * 256 + threadIdx.x;
    if (i < NN) { rowptr[i] += bsum[blockIdx.x]; c[i] = 0; }
    if (i == 0) rowptr[NN] = NE;
}

// XCD-partitioned fill: block b (XCD b&7) owns dst range of 12500 nodes.
__global__ __launch_bounds__(256) void k_fill_x(const int* __restrict__ src,
                                                const int* __restrict__ dst,
                                                const int* __restrict__ rowptr,
                                                int* __restrict__ cur,
                                                int* __restrict__ col) {
    const int b  = blockIdx.x;
    const int lo = (b & 7) * NPX;
    const int hi = lo + NPX;
    const int q  = b >> 3;
    const int e0 = q * EPC;
    const int e1 = (e0 + EPC < NE) ? e0 + EPC : NE;
    for (int e = e0 + threadIdx.x; e < e1; e += 256) {
        int d = dst[e];
        if (d >= lo && d < hi) {
            int s = src[e];
            int pos = rowptr[d] + atomicAdd(&cur[d], 1);
            col[pos] = s;
        }
    }
}

// Pack W2 into k-pair half2: Wp[k2][c] = (W2[2k2][c], W2[2k2+1][c]).
__global__ __launch_bounds__(256) void k_w2pack(const float* __restrict__ W2,
                                                unsigned* __restrict__ Wp) {
    int idx = blockIdx.x * 256 + threadIdx.x;   // 64*128
    if (idx >= 64 * 128) return;
    int k2 = idx >> 7, c = idx & 127;
    __half2 h = __floats2half2_rn(W2[(2 * k2) * HID + c],
                                  (float)W2[(2 * k2 + 1) * HID + c]);
    Wp[idx] = __builtin_bit_cast(unsigned, h);
}

// Layer-1 GEMM, 32-row tile (LDS 21.2KB -> 7 blocks/CU, 28 waves).
// Thread (cg=t&31, rg=t>>5) owns 4 rows x 4 cols. X from LDS via b64
// broadcast reads; W float4 from L2-hot 84KB. Epilogue: fp16(dinv*y).
template<int K, int KP>
__global__ __launch_bounds__(256) void k_gemm1(const float* __restrict__ X,
                                               const float* __restrict__ W,
                                               const float* __restrict__ dinv,
                                               __half* __restrict__ Yh) {
    __shared__ float Xs[32 * KP];
    const int tid = threadIdx.x;
    const long base = (long)blockIdx.x * 32;     // NN%32==0: no tail

    const float* Xg = X + base * K;
    for (int i = tid; i < 32 * K; i += 256) {
        int r = i / K, c = i % K;
        Xs[r * KP + c] = Xg[i];
    }
    __syncthreads();

    const int cg = tid & 31;
    const int rg = tid >> 5;
    const float* Wp = W + 4 * cg;
    const float* Xrow = &Xs[rg * 4 * KP];

    float acc[4][4];
#pragma unroll
    for (int r = 0; r < 4; ++r)
#pragma unroll
        for (int c = 0; c < 4; ++c) acc[r][c] = 0.0f;

    int k = 0;
    for (; k + 2 <= K; k += 2) {
        float4 w0 = *(const float4*)(Wp + (k + 0) * HID);
        float4 w1 = *(const float4*)(Wp + (k + 1) * HID);
#pragma unroll
        for (int r = 0; r < 4; ++r) {
            float2 xv = *(const float2*)&Xrow[r * KP + k];   // b64 broadcast
            acc[r][0] += xv.x * w0.x + xv.y * w1.x;
            acc[r][1] += xv.x * w0.y + xv.y * w1.y;
            acc[r][2] += xv.x * w0.z + xv.y * w1.z;
            acc[r][3] += xv.x * w0.w + xv.y * w1.w;
        }
    }
    if (k < K) {                                   // K odd tail
        float4 wt = *(const float4*)(Wp + k * HID);
#pragma unroll
        for (int r = 0; r < 4; ++r) {
            float xs = Xrow[r * KP + k];
            acc[r][0] += xs * wt.x;
            acc[r][1] += xs * wt.y;
            acc[r][2] += xs * wt.z;
            acc[r][3] += xs * wt.w;
        }
    }

#pragma unroll
    for (int r = 0; r < 4; ++r) {
        long row = base + rg * 4 + r;
        float d = dinv[row];
        __half2 p0 = __floats2half2_rn(acc[r][0] * d, acc[r][1] * d);
        __half2 p1 = __floats2half2_rn(acc[r][2] * d, acc[r][3] * d);
        uint2 uv;
        uv.x = *reinterpret_cast<unsigned int*>(&p0);
        uv.y = *reinterpret_cast<unsigned int*>(&p1);
        *reinterpret_cast<uint2*>(&Yh[row * HID + 4 * cg]) = uv;
    }
}

// Gather sum of pre-scaled fp16 rows (incl. self); lane j owns cols 2j,2j+1.
__device__ __forceinline__ void gather_row_h(const __half2* __restrict__ H2,
                                             const int* __restrict__ rowptr,
                                             const int* __restrict__ col,
                                             int i, int j,
                                             float& a0, float& a1) {
    int k = rowptr[i];
    const int end = rowptr[i + 1];
    float2 self = __half22float2(H2[(size_t)i * 64 + j]);
    a0 = self.x;
    a1 = self.y;
    for (; k + 8 <= end; k += 8) {
        int s[8];
#pragma unroll
        for (int u = 0; u < 8; ++u)
            s[u] = __builtin_nontemporal_load(&col[k + u]);
        __half2 h[8];
#pragma unroll
        for (int u = 0; u < 8; ++u) h[u] = H2[(size_t)s[u] * 64 + j];
#pragma unroll
        for (int u = 0; u < 8; ++u) {
            float2 f = __half22float2(h[u]);
            a0 += f.x;
            a1 += f.y;
        }
    }
    for (; k < end; ++k) {
        int cs = __builtin_nontemporal_load(&col[k]);
        float2 f = __half22float2(H2[(size_t)cs * 64 + j]);
        a0 += f.x;
        a1 += f.y;
    }
}

// Pure gather, 256 threads = 4 waves, wave handles 4 nodes (16/block).
// MODE 0: out = fp16( di * relu(di*a + b1) );  MODE 1: out = fp16( di * a ).
template<int MODE>
__global__ __launch_bounds__(256) void k_aggP(const __half* __restrict__ Hh,
                                              const int* __restrict__ rowptr,
                                              const int* __restrict__ col,
                                              const float* __restrict__ dinv,
                                              const float* __restrict__ bias,
                                              __half* __restrict__ Oh) {
    const int j    = threadIdx.x & 63;
    const int wvid = threadIdx.x >> 6;
    const int base = blockIdx.x * 16 + wvid * 4;
    const __half2* H2 = (const __half2*)Hh;
    float2 bb = make_float2(0.f, 0.f);
    if (MODE == 0) bb = ((const float2*)bias)[j];

#pragma unroll
    for (int n = 0; n < 4; ++n) {
        const int i = base + n;
        const float di = dinv[i];
        float a0, a1;
        gather_row_h(H2, rowptr, col, i, j, a0, a1);
        float r0, r1;
        if (MODE == 0) {
            r0 = di * fmaxf(di * a0 + bb.x, 0.0f);
            r1 = di * fmaxf(di * a1 + bb.y, 0.0f);
        } else {
            r0 = di * a0;
            r1 = di * a1;
        }
        ((__half2*)Oh)[(size_t)i * 64 + j] = __floats2half2_rn(r0, r1);
    }
}

// Dense tail: out[i] = relu(u[i] @ W2 + b2) @ W3 + b3, u fp16, dot2 math.
__global__ __launch_bounds__(256) void k_tail(const unsigned* __restrict__ Ug,
                                              const unsigned* __restrict__ W2p,
                                              const float* __restrict__ b2,
                                              const float* __restrict__ W3,
                                              const float* __restrict__ b3,
                                              float* __restrict__ out) {
    __shared__ unsigned Xs[64 * 66];         // [row][k2], stride 66
    __shared__ unsigned Ws[64 * 128];        // [k2][c]
    const int tid = threadIdx.x;
    const long base = (long)blockIdx.x * 64;

#pragma unroll
    for (int i = 0; i < 4; ++i) {
        int li = tid + i * 256;               // uint4 index, 1024 total
        int row = li >> 4;
        int q4  = li & 15;
        uint4 v = make_uint4(0, 0, 0, 0);
        if (base + row < NN)
            v = *(const uint4*)&Ug[(base + row) * 64 + q4 * 4];
        Xs[row * 66 + q4 * 4 + 0] = v.x;
        Xs[row * 66 + q4 * 4 + 1] = v.y;
        Xs[row * 66 + q4 * 4 + 2] = v.z;
        Xs[row * 66 + q4 * 4 + 3] = v.w;
    }
#pragma unroll
    for (int i = 0; i < 8; ++i) {
        int li = tid + i * 256;               // uint4 index, 2048 total
        *(uint4*)&Ws[li * 4] = *(const uint4*)&W2p[li * 4];
    }
    __syncthreads();

    const int cg = tid & 31;
    const int rg = tid >> 5;

    float acc[8][4];
#pragma unroll
    for (int r = 0; r < 8; ++r)
#pragma unroll
        for (int c = 0; c < 4; ++c) acc[r][c] = 0.0f;

    for (int k2 = 0; k2 < 64; k2 += 2) {
        uint4 w0 = *(const uint4*)&Ws[k2 * 128 + 4 * cg];
        uint4 w1 = *(const uint4*)&Ws[(k2 + 1) * 128 + 4 * cg];
#pragma unroll
        for (int r = 0; r < 8; ++r) {
            uint2 xp = *(const uint2*)&Xs[(rg * 8 + r) * 66 + k2];
            acc[r][0] = fdot2u(xp.x, w0.x, acc[r][0]);
            acc[r][1] = fdot2u(xp.x, w0.y, acc[r][1]);
            acc[r][2] = fdot2u(xp.x, w0.z, acc[r][2]);
            acc[r][3] = fdot2u(xp.x, w0.w, acc[r][3]);
            acc[r][0] = fdot2u(xp.y, w1.x, acc[r][0]);
            acc[r][1] = fdot2u(xp.y, w1.y, acc[r][1]);
            acc[r][2] = fdot2u(xp.y, w1.z, acc[r][2]);
            acc[r][3] = fdot2u(xp.y, w1.w, acc[r][3]);
        }
    }

    const float4 bb = *(const float4*)&b2[4 * cg];
    float2 w3v[4];
#pragma unroll
    for (int c = 0; c < 4; ++c)
        w3v[c] = *(const float2*)&W3[(4 * cg + c) * 2];
    const float b30 = b3[0], b31 = b3[1];

#pragma unroll
    for (int r = 0; r < 8; ++r) {
        float h0 = fmaxf(acc[r][0] + bb.x, 0.f);
        float h1 = fmaxf(acc[r][1] + bb.y, 0.f);
        float h2 = fmaxf(acc[r][2] + bb.z, 0.f);
        float h3 = fmaxf(acc[r][3] + bb.w, 0.f);
        float p0 = h0 * w3v[0].x + h1 * w3v[1].x + h2 * w3v[2].x + h3 * w3v[3].x;
        float p1 = h0 * w3v[0].y + h1 * w3v[1].y + h2 * w3v[2].y + h3 * w3v[3].y;
#pragma unroll
        for (int m = 1; m < 32; m <<= 1) {
            p0 += __shfl_xor(p0, m);
            p1 += __shfl_xor(p1, m);
        }
        long row = base + rg * 8 + r;
        if (cg == 0 && row < NN)
            ((float2*)out)[row] = make_float2(p0 + b30, p1 + b31);
    }
}

extern "C" void kernel_launch(void* const* d_in, const int* in_sizes, int n_in,
                              void* d_out, int out_size, void* d_ws, size_t ws_size,
                              hipStream_t stream) {
    const float* x   = (const float*)d_in[0];
    const int*   ei  = (const int*)d_in[1];
    const float* W1  = (const float*)d_in[2];
    const float* b1  = (const float*)d_in[3];
    const float* W2  = (const float*)d_in[4];
    const float* b2  = (const float*)d_in[5];
    const float* W3  = (const float*)d_in[6];
    const float* b3  = (const float*)d_in[7];
    float* out = (float*)d_out;

    const int* srcA = ei;
    const int* dstA = ei + NE;

    char* p = (char*)d_ws;
    auto alloc = [&](size_t bytes) {
        char* r = p;
        p += (bytes + 255) & ~(size_t)255;
        return r;
    };
    float*    dinv   = (float*)alloc(NN * 4);
    int*      counts = (int*)  alloc(NN * 4);        // reused as fill cursor
    int*      rowptr = (int*)  alloc((NN + 1) * 4);
    int*      bsum   = (int*)  alloc(512 * 4);
    int*      col    = (int*)  alloc((size_t)NE * 4);
    unsigned* w2pk   = (unsigned*)alloc(64 * 128 * 4);
    __half*   hhat   = (__half*)alloc((size_t)NN * HID * 2);  // dinv*h1
    __half*   h2hat  = (__half*)alloc((size_t)NN * HID * 2);  // dinv*h2
    __half*   ubuf   = (__half*)alloc((size_t)NN * HID * 2);  // A-hat h2

    const int nb_n = (NN + 255) / 256;
    const int nb_g = (NN + 63) / 64;

    // ---- CSR build + weight pack ----
    k_zero_counts<<<nb_n, 256, 0, stream>>>(counts);
    k_hist_x<<<8 * NCHUNK, 256, 0, stream>>>(dstA, counts);
    k_w2pack<<<32, 256, 0, stream>>>(W2, w2pk);
    k_scanA<<<nb_n, 256, 0, stream>>>(counts, rowptr, bsum, dinv);
    k_scanB<<<1, 512, 0, stream>>>(bsum, nb_n);
    k_scanC<<<nb_n, 256, 0, stream>>>(rowptr, bsum, counts);
    k_fill_x<<<8 * NCHUNK, 256, 0, stream>>>(srcA, dstA, rowptr, counts, col);

    // ---- layer 1 GEMM -> hhat (32-row tiles) ----
    k_gemm1<FIN, 166><<<NN / 32, 256, 0, stream>>>(x, W1, dinv, hhat);

    // ---- agg1 (pure) -> h2hat ----
    k_aggP<0><<<NN / 16, 256, 0, stream>>>(hhat, rowptr, col, dinv, b1, h2hat);

    // ---- agg2 (pure) -> u ----
    k_aggP<1><<<NN / 16, 256, 0, stream>>>(h2hat, rowptr, col, dinv, nullptr, ubuf);

    // ---- tail: relu(u@W2+b2)@W3+b3 ----
    k_tail<<<nb_g, 256, 0, stream>>>((const unsigned*)ubuf, w2pk, b2, W3, b3, out);
}

// Round 13
// 400.760 us; speedup vs baseline: 1.1618x; 1.1618x over previous
//
#include <hip/hip_runtime.h>
#include <hip/hip_fp16.h>

// EllipticGNN: 2-layer GCN + linear head, f32 compute.
// fp16 pre-scaled gather rows; pure-gather aggs (R11 form); dense dot2 tail.
// R13: gemm1 keeps 64-row/8x4 shape but stages X as fp16 in LDS
// (21.5KB -> ~7 blocks/CU) for latency hiding without extra W traffic.

constexpr int NN   = 100000;
constexpr int NE   = 1600000;
constexpr int FIN  = 165;
constexpr int HID  = 128;
constexpr int NPX  = NN / 8;            // 12500 nodes per XCD partition
constexpr int NCHUNK = 250;             // edge chunks per XCD
constexpr int EPC  = (NE + NCHUNK - 1) / NCHUNK;   // 6400 edges per chunk

typedef _Float16 h2v __attribute__((ext_vector_type(2)));

__device__ __forceinline__ float fdot2u(unsigned a, unsigned b, float c) {
#if __has_builtin(__builtin_amdgcn_fdot2)
    return __builtin_amdgcn_fdot2(__builtin_bit_cast(h2v, a),
                                  __builtin_bit_cast(h2v, b), c, false);
#else
    __half2 ah = __builtin_bit_cast(__half2, a);
    __half2 bh = __builtin_bit_cast(__half2, b);
    float2 af = __half22float2(ah), bf = __half22float2(bh);
    return fmaf(af.x, bf.x, fmaf(af.y, bf.y, c));
#endif
}

__global__ __launch_bounds__(256) void k_zero_counts(int* __restrict__ c) {
    int i = blockIdx.x * 256 + threadIdx.x;
    if (i < NN) c[i] = 0;
}

__global__ __launch_bounds__(256) void k_hist(const int* __restrict__ dst,
                                              int* __restrict__ c) {
    int i = blockIdx.x * 256 + threadIdx.x;
    if (i < NE) atomicAdd(&c[dst[i]], 1);
}

// scanA + fused dinv.
__global__ __launch_bounds__(256) void k_scanA(const int* __restrict__ c,
                                               int* __restrict__ rowptr,
                                               int* __restrict__ bsum,
                                               float* __restrict__ dinv) {
    __shared__ int s[256];
    int t = threadIdx.x;
    int i = blockIdx.x * 256 + t;
    int v = (i < NN) ? c[i] : 0;
    if (i < NN) dinv[i] = rsqrtf((float)v + 1.0f);   // +1 self-loop
    s[t] = v; __syncthreads();
    for (int off = 1; off < 256; off <<= 1) {
        int add = (t >= off) ? s[t - off] : 0;
        __syncthreads();
        s[t] += add;
        __syncthreads();
    }
    if (i < NN) rowptr[i] = s[t] - v;
    if (t == 255) bsum[blockIdx.x] = s[255];
}

__global__ __launch_bounds__(512) void k_scanB(int* __restrict__ bsum, int nb) {
    __shared__ int s[512];
    int t = threadIdx.x;
    int v = (t < nb) ? bsum[t] : 0;
    s[t] = v; __syncthreads();
    for (int off = 1; off < 512; off <<= 1) {
        int add = (t >= off) ? s[t - off] : 0;
        __syncthreads();
        s[t] += add;
        __syncthreads();
    }
    if (t < nb) bsum[t] = s[t] - v;
}

__global__ __launch_bounds__(256) void k_scanC(int* __restrict__ rowptr,
                                               const int* __restrict__ bsum,
                                               int* __restrict__ c) {
    int i = blockIdx.x * 256 + threadIdx.x;
    if (i < NN) { rowptr[i] += bsum[blockIdx.x]; c[i] = 0; }
    if (i == 0) rowptr[NN] = NE;
}

// XCD-partitioned fill: block b (XCD b&7) owns dst range of 12500 nodes.
__global__ __launch_bounds__(256) void k_fill_x(const int* __restrict__ src,
                                                const int* __restrict__ dst,
                                                const int* __restrict__ rowptr,
                                                int* __restrict__ cur,
                                                int* __restrict__ col) {
    const int b  = blockIdx.x;
    const int lo = (b & 7) * NPX;
    const int hi = lo + NPX;
    const int q  = b >> 3;
    const int e0 = q * EPC;
    const int e1 = (e0 + EPC < NE) ? e0 + EPC : NE;
    for (int e = e0 + threadIdx.x; e < e1; e += 256) {
        int d = dst[e];
        if (d >= lo && d < hi) {
            int s = src[e];
            int pos = rowptr[d] + atomicAdd(&cur[d], 1);
            col[pos] = s;
        }
    }
}

// Pack W2 into k-pair half2: Wp[k2][c] = (W2[2k2][c], W2[2k2+1][c]).
__global__ __launch_bounds__(256) void k_w2pack(const float* __restrict__ W2,
                                                unsigned* __restrict__ Wp) {
    int idx = blockIdx.x * 256 + threadIdx.x;   // 64*128
    if (idx >= 64 * 128) return;
    int k2 = idx >> 7, c = idx & 127;
    __half2 h = __floats2half2_rn(W2[(2 * k2) * HID + c],
                                  (float)W2[(2 * k2 + 1) * HID + c]);
    Wp[idx] = __builtin_bit_cast(unsigned, h);
}

// Layer-1 GEMM: 64-row tile, 8 rows x 4 cols per thread (good W amortize),
// X staged fp16 in LDS (21.5KB -> ~7 blocks/CU). W f32 float4 (L1/L2 hot).
// Epilogue: fp16(dinv*y).
__global__ __launch_bounds__(256) void k_gemm1h(const float* __restrict__ X,
                                                const float* __restrict__ W,
                                                const float* __restrict__ dinv,
                                                __half* __restrict__ Yh) {
    constexpr int K = FIN;           // 165
    constexpr int KP = 168;          // half stride; 336B rows (8B aligned)
    __shared__ __half Xs[64 * KP];
    const int tid = threadIdx.x;
    const long base = (long)blockIdx.x * 64;
    const int rows = (NN - base < 64) ? (int)(NN - base) : 64;

    const float* Xg = X + base * K;
    for (int i = tid; i < rows * K; i += 256) {
        int r = i / K, c = i % K;
        Xs[r * KP + c] = __float2half(Xg[i]);
    }
    for (int i = tid; i < 64 * 3; i += 256) {        // zero pad c=165..167
        int r = i / 3, c = K + i % 3;
        Xs[r * KP + c] = __float2half(0.f);
    }
    if (rows < 64) {                                  // last block only
        for (int i = tid; i < (64 - rows) * KP; i += 256)
            Xs[rows * KP + i] = __float2half(0.f);
    }
    __syncthreads();

    const int cg = tid & 31;
    const int rg = tid >> 5;
    const float* Wp = W + 4 * cg;
    const __half* Xrow = &Xs[rg * 8 * KP];

    float acc[8][4];
#pragma unroll
    for (int r = 0; r < 8; ++r)
#pragma unroll
        for (int c = 0; c < 4; ++c) acc[r][c] = 0.0f;

    int k = 0;
    for (; k + 4 <= K - 1; k += 4) {                 // k = 0..160 (41 iters)
        float4 w0 = *(const float4*)(Wp + (k + 0) * HID);
        float4 w1 = *(const float4*)(Wp + (k + 1) * HID);
        float4 w2 = *(const float4*)(Wp + (k + 2) * HID);
        float4 w3 = *(const float4*)(Wp + (k + 3) * HID);
#pragma unroll
        for (int r = 0; r < 8; ++r) {
            uint2 xp = *(const uint2*)&Xrow[r * KP + k];   // 4 halves, 8B
            float2 xa = __half22float2(__builtin_bit_cast(__half2, xp.x));
            float2 xb = __half22float2(__builtin_bit_cast(__half2, xp.y));
            acc[r][0] += xa.x * w0.x + xa.y * w1.x + xb.x * w2.x + xb.y * w3.x;
            acc[r][1] += xa.x * w0.y + xa.y * w1.y + xb.x * w2.y + xb.y * w3.y;
            acc[r][2] += xa.x * w0.z + xa.y * w1.z + xb.x * w2.z + xb.y * w3.z;
            acc[r][3] += xa.x * w0.w + xa.y * w1.w + xb.x * w2.w + xb.y * w3.w;
        }
    }
    {   // tail k = 164
        float4 wt = *(const float4*)(Wp + (K - 1) * HID);
#pragma unroll
        for (int r = 0; r < 8; ++r) {
            float xs = __half2float(Xrow[r * KP + (K - 1)]);
            acc[r][0] += xs * wt.x;
            acc[r][1] += xs * wt.y;
            acc[r][2] += xs * wt.z;
            acc[r][3] += xs * wt.w;
        }
    }

#pragma unroll
    for (int r = 0; r < 8; ++r) {
        long row = base + rg * 8 + r;
        if (row < NN) {
            float d = dinv[row];
            __half2 p0 = __floats2half2_rn(acc[r][0] * d, acc[r][1] * d);
            __half2 p1 = __floats2half2_rn(acc[r][2] * d, acc[r][3] * d);
            uint2 uv;
            uv.x = *reinterpret_cast<unsigned int*>(&p0);
            uv.y = *reinterpret_cast<unsigned int*>(&p1);
            *reinterpret_cast<uint2*>(&Yh[row * HID + 4 * cg]) = uv;
        }
    }
}

// Gather sum of pre-scaled fp16 rows (incl. self); lane j owns cols 2j,2j+1.
__device__ __forceinline__ void gather_row_h(const __half2* __restrict__ H2,
                                             const int* __restrict__ rowptr,
                                             const int* __restrict__ col,
                                             int i, int j,
                                             float& a0, float& a1) {
    int k = rowptr[i];
    const int end = rowptr[i + 1];
    float2 self = __half22float2(H2[(size_t)i * 64 + j]);
    a0 = self.x;
    a1 = self.y;
    for (; k + 8 <= end; k += 8) {
        int s[8];
#pragma unroll
        for (int u = 0; u < 8; ++u)
            s[u] = __builtin_nontemporal_load(&col[k + u]);
        __half2 h[8];
#pragma unroll
        for (int u = 0; u < 8; ++u) h[u] = H2[(size_t)s[u] * 64 + j];
#pragma unroll
        for (int u = 0; u < 8; ++u) {
            float2 f = __half22float2(h[u]);
            a0 += f.x;
            a1 += f.y;
        }
    }
    for (; k < end; ++k) {
        int cs = __builtin_nontemporal_load(&col[k]);
        float2 f = __half22float2(H2[(size_t)cs * 64 + j]);
        a0 += f.x;
        a1 += f.y;
    }
}

// Pure gather, wave per 4 nodes (R11 proven form).
// MODE 0: out = fp16( di * relu(di*a + b1) );  MODE 1: out = fp16( di * a ).
template<int MODE>
__global__ __launch_bounds__(64) void k_aggP(const __half* __restrict__ Hh,
                                             const int* __restrict__ rowptr,
                                             const int* __restrict__ col,
                                             const float* __restrict__ dinv,
                                             const float* __restrict__ bias,
                                             __half* __restrict__ Oh) {
    const int j = threadIdx.x;
    const int base = blockIdx.x * 4;
    const __half2* H2 = (const __half2*)Hh;
    float2 bb = make_float2(0.f, 0.f);
    if (MODE == 0) bb = ((const float2*)bias)[j];

#pragma unroll
    for (int n = 0; n < 4; ++n) {
        const int i = base + n;
        const float di = dinv[i];
        float a0, a1;
        gather_row_h(H2, rowptr, col, i, j, a0, a1);
        float r0, r1;
        if (MODE == 0) {
            r0 = di * fmaxf(di * a0 + bb.x, 0.0f);
            r1 = di * fmaxf(di * a1 + bb.y, 0.0f);
        } else {
            r0 = di * a0;
            r1 = di * a1;
        }
        ((__half2*)Oh)[(size_t)i * 64 + j] = __floats2half2_rn(r0, r1);
    }
}

// Dense tail: out[i] = relu(u[i] @ W2 + b2) @ W3 + b3, u fp16, dot2 math.
__global__ __launch_bounds__(256) void k_tail(const unsigned* __restrict__ Ug,
                                              const unsigned* __restrict__ W2p,
                                              const float* __restrict__ b2,
                                              const float* __restrict__ W3,
                                              const float* __restrict__ b3,
                                              float* __restrict__ out) {
    __shared__ unsigned Xs[64 * 66];         // [row][k2], stride 66
    __shared__ unsigned Ws[64 * 128];        // [k2][c]
    const int tid = threadIdx.x;
    const long base = (long)blockIdx.x * 64;

#pragma unroll
    for (int i = 0; i < 4; ++i) {
        int li = tid + i * 256;               // uint4 index, 1024 total
        int row = li >> 4;
        int q4  = li & 15;
        uint4 v = make_uint4(0, 0, 0, 0);
        if (base + row < NN)
            v = *(const uint4*)&Ug[(base + row) * 64 + q4 * 4];
        Xs[row * 66 + q4 * 4 + 0] = v.x;
        Xs[row * 66 + q4 * 4 + 1] = v.y;
        Xs[row * 66 + q4 * 4 + 2] = v.z;
        Xs[row * 66 + q4 * 4 + 3] = v.w;
    }
#pragma unroll
    for (int i = 0; i < 8; ++i) {
        int li = tid + i * 256;               // uint4 index, 2048 total
        *(uint4*)&Ws[li * 4] = *(const uint4*)&W2p[li * 4];
    }
    __syncthreads();

    const int cg = tid & 31;
    const int rg = tid >> 5;

    float acc[8][4];
#pragma unroll
    for (int r = 0; r < 8; ++r)
#pragma unroll
        for (int c = 0; c < 4; ++c) acc[r][c] = 0.0f;

    for (int k2 = 0; k2 < 64; k2 += 2) {
        uint4 w0 = *(const uint4*)&Ws[k2 * 128 + 4 * cg];
        uint4 w1 = *(const uint4*)&Ws[(k2 + 1) * 128 + 4 * cg];
#pragma unroll
        for (int r = 0; r < 8; ++r) {
            uint2 xp = *(const uint2*)&Xs[(rg * 8 + r) * 66 + k2];
            acc[r][0] = fdot2u(xp.x, w0.x, acc[r][0]);
            acc[r][1] = fdot2u(xp.x, w0.y, acc[r][1]);
            acc[r][2] = fdot2u(xp.x, w0.z, acc[r][2]);
            acc[r][3] = fdot2u(xp.x, w0.w, acc[r][3]);
            acc[r][0] = fdot2u(xp.y, w1.x, acc[r][0]);
            acc[r][1] = fdot2u(xp.y, w1.y, acc[r][1]);
            acc[r][2] = fdot2u(xp.y, w1.z, acc[r][2]);
            acc[r][3] = fdot2u(xp.y, w1.w, acc[r][3]);
        }
    }

    const float4 bb = *(const float4*)&b2[4 * cg];
    float2 w3v[4];
#pragma unroll
    for (int c = 0; c < 4; ++c)
        w3v[c] = *(const float2*)&W3[(4 * cg + c) * 2];
    const float b30 = b3[0], b31 = b3[1];

#pragma unroll
    for (int r = 0; r < 8; ++r) {
        float h0 = fmaxf(acc[r][0] + bb.x, 0.f);
        float h1 = fmaxf(acc[r][1] + bb.y, 0.f);
        float h2 = fmaxf(acc[r][2] + bb.z, 0.f);
        float h3 = fmaxf(acc[r][3] + bb.w, 0.f);
        float p0 = h0 * w3v[0].x + h1 * w3v[1].x + h2 * w3v[2].x + h3 * w3v[3].x;
        float p1 = h0 * w3v[0].y + h1 * w3v[1].y + h2 * w3v[2].y + h3 * w3v[3].y;
#pragma unroll
        for (int m = 1; m < 32; m <<= 1) {
            p0 += __shfl_xor(p0, m);
            p1 += __shfl_xor(p1, m);
        }
        long row = base + rg * 8 + r;
        if (cg == 0 && row < NN)
            ((float2*)out)[row] = make_float2(p0 + b30, p1 + b31);
    }
}

extern "C" void kernel_launch(void* const* d_in, const int* in_sizes, int n_in,
                              void* d_out, int out_size, void* d_ws, size_t ws_size,
                              hipStream_t stream) {
    const float* x   = (const float*)d_in[0];
    const int*   ei  = (const int*)d_in[1];
    const float* W1  = (const float*)d_in[2];
    const float* b1  = (const float*)d_in[3];
    const float* W2  = (const float*)d_in[4];
    const float* b2  = (const float*)d_in[5];
    const float* W3  = (const float*)d_in[6];
    const float* b3  = (const float*)d_in[7];
    float* out = (float*)d_out;

    const int* srcA = ei;
    const int* dstA = ei + NE;

    char* p = (char*)d_ws;
    auto alloc = [&](size_t bytes) {
        char* r = p;
        p += (bytes + 255) & ~(size_t)255;
        return r;
    };
    float*    dinv   = (float*)alloc(NN * 4);
    int*      counts = (int*)  alloc(NN * 4);        // reused as fill cursor
    int*      rowptr = (int*)  alloc((NN + 1) * 4);
    int*      bsum   = (int*)  alloc(512 * 4);
    int*      col    = (int*)  alloc((size_t)NE * 4);
    unsigned* w2pk   = (unsigned*)alloc(64 * 128 * 4);
    __half*   hhat   = (__half*)alloc((size_t)NN * HID * 2);  // dinv*h1
    __half*   h2hat  = (__half*)alloc((size_t)NN * HID * 2);  // dinv*h2
    __half*   ubuf   = (__half*)alloc((size_t)NN * HID * 2);  // A-hat h2

    const int nb_n = (NN + 255) / 256;
    const int nb_e = (NE + 255) / 256;
    const int nb_g = (NN + 63) / 64;

    // ---- CSR build + weight pack ----
    k_zero_counts<<<nb_n, 256, 0, stream>>>(counts);
    k_hist<<<nb_e, 256, 0, stream>>>(dstA, counts);
    k_w2pack<<<32, 256, 0, stream>>>(W2, w2pk);
    k_scanA<<<nb_n, 256, 0, stream>>>(counts, rowptr, bsum, dinv);
    k_scanB<<<1, 512, 0, stream>>>(bsum, nb_n);
    k_scanC<<<nb_n, 256, 0, stream>>>(rowptr, bsum, counts);
    k_fill_x<<<8 * NCHUNK, 256, 0, stream>>>(srcA, dstA, rowptr, counts, col);

    // ---- layer 1 GEMM -> hhat ----
    k_gemm1h<<<nb_g, 256, 0, stream>>>(x, W1, dinv, hhat);

    // ---- agg1 (pure) -> h2hat ----
    k_aggP<0><<<NN / 4, 64, 0, stream>>>(hhat, rowptr, col, dinv, b1, h2hat);

    // ---- agg2 (pure) -> u ----
    k_aggP<1><<<NN / 4, 64, 0, stream>>>(h2hat, rowptr, col, dinv, nullptr, ubuf);

    // ---- tail: relu(u@W2+b2)@W3+b3 ----
    k_tail<<<nb_g, 256, 0, stream>>>((const unsigned*)ubuf, w2pk, b2, W3, b3, out);
}

// Round 14
// 375.727 us; speedup vs baseline: 1.2392x; 1.0666x over previous
//
#include <hip/hip_runtime.h>
#include <hip/hip_fp16.h>

// EllipticGNN: 2-layer GCN + linear head, f32 accumulate.
// fp16 pre-scaled gather rows; pure-gather aggs; dense dot2 tail.
// R14: gemm1 uses v_dot2_f32_f16 with fp16-packed W1 (k-pair half2),
// halving VALU ops vs the f32 FMA + cvt path.

constexpr int NN   = 100000;
constexpr int NE   = 1600000;
constexpr int FIN  = 165;
constexpr int HID  = 128;
constexpr int NPX  = NN / 8;            // 12500 nodes per XCD partition
constexpr int NCHUNK = 250;             // edge chunks per XCD
constexpr int EPC  = (NE + NCHUNK - 1) / NCHUNK;   // 6400 edges per chunk
constexpr int K2_1 = (FIN + 1) / 2;     // 83 k-pairs for layer 1

typedef _Float16 h2v __attribute__((ext_vector_type(2)));

__device__ __forceinline__ float fdot2u(unsigned a, unsigned b, float c) {
#if __has_builtin(__builtin_amdgcn_fdot2)
    return __builtin_amdgcn_fdot2(__builtin_bit_cast(h2v, a),
                                  __builtin_bit_cast(h2v, b), c, false);
#else
    __half2 ah = __builtin_bit_cast(__half2, a);
    __half2 bh = __builtin_bit_cast(__half2, b);
    float2 af = __half22float2(ah), bf = __half22float2(bh);
    return fmaf(af.x, bf.x, fmaf(af.y, bf.y, c));
#endif
}

__global__ __launch_bounds__(256) void k_zero_counts(int* __restrict__ c) {
    int i = blockIdx.x * 256 + threadIdx.x;
    if (i < NN) c[i] = 0;
}

__global__ __launch_bounds__(256) void k_hist(const int* __restrict__ dst,
                                              int* __restrict__ c) {
    int i = blockIdx.x * 256 + threadIdx.x;
    if (i < NE) atomicAdd(&c[dst[i]], 1);
}

// scanA + fused dinv.
__global__ __launch_bounds__(256) void k_scanA(const int* __restrict__ c,
                                               int* __restrict__ rowptr,
                                               int* __restrict__ bsum,
                                               float* __restrict__ dinv) {
    __shared__ int s[256];
    int t = threadIdx.x;
    int i = blockIdx.x * 256 + t;
    int v = (i < NN) ? c[i] : 0;
    if (i < NN) dinv[i] = rsqrtf((float)v + 1.0f);   // +1 self-loop
    s[t] = v; __syncthreads();
    for (int off = 1; off < 256; off <<= 1) {
        int add = (t >= off) ? s[t - off] : 0;
        __syncthreads();
        s[t] += add;
        __syncthreads();
    }
    if (i < NN) rowptr[i] = s[t] - v;
    if (t == 255) bsum[blockIdx.x] = s[255];
}

__global__ __launch_bounds__(512) void k_scanB(int* __restrict__ bsum, int nb) {
    __shared__ int s[512];
    int t = threadIdx.x;
    int v = (t < nb) ? bsum[t] : 0;
    s[t] = v; __syncthreads();
    for (int off = 1; off < 512; off <<= 1) {
        int add = (t >= off) ? s[t - off] : 0;
        __syncthreads();
        s[t] += add;
        __syncthreads();
    }
    if (t < nb) bsum[t] = s[t] - v;
}

__global__ __launch_bounds__(256) void k_scanC(int* __restrict__ rowptr,
                                               const int* __restrict__ bsum,
                                               int* __restrict__ c) {
    int i = blockIdx.x * 256 + threadIdx.x;
    if (i < NN) { rowptr[i] += bsum[blockIdx.x]; c[i] = 0; }
    if (i == 0) rowptr[NN] = NE;
}

// XCD-partitioned fill: block b (XCD b&7) owns dst range of 12500 nodes.
__global__ __launch_bounds__(256) void k_fill_x(const int* __restrict__ src,
                                                const int* __restrict__ dst,
                                                const int* __restrict__ rowptr,
                                                int* __restrict__ cur,
                                                int* __restrict__ col) {
    const int b  = blockIdx.x;
    const int lo = (b & 7) * NPX;
    const int hi = lo + NPX;
    const int q  = b >> 3;
    const int e0 = q * EPC;
    const int e1 = (e0 + EPC < NE) ? e0 + EPC : NE;
    for (int e = e0 + threadIdx.x; e < e1; e += 256) {
        int d = dst[e];
        if (d >= lo && d < hi) {
            int s = src[e];
            int pos = rowptr[d] + atomicAdd(&cur[d], 1);
            col[pos] = s;
        }
    }
}

// Pack W2 into k-pair half2: Wp[k2][c] = (W2[2k2][c], W2[2k2+1][c]).
__global__ __launch_bounds__(256) void k_w2pack(const float* __restrict__ W2,
                                                unsigned* __restrict__ Wp) {
    int idx = blockIdx.x * 256 + threadIdx.x;   // 64*128
    if (idx >= 64 * 128) return;
    int k2 = idx >> 7, c = idx & 127;
    __half2 h = __floats2half2_rn(W2[(2 * k2) * HID + c],
                                  (float)W2[(2 * k2 + 1) * HID + c]);
    Wp[idx] = __builtin_bit_cast(unsigned, h);
}

// Pack W1 into k-pair half2: Wp[k2][c] = (W1[2k2][c], W1[2k2+1][c]), 
// k2 in [0,83); last pair's second element is zero (K=165 odd).
__global__ __launch_bounds__(256) void k_w1pack(const float* __restrict__ W1,
                                                unsigned* __restrict__ Wp) {
    int idx = blockIdx.x * 256 + threadIdx.x;   // 83*128 = 10624
    if (idx >= K2_1 * HID) return;
    int k2 = idx / HID, c = idx % HID;
    float lo = W1[(2 * k2) * HID + c];
    float hi = (2 * k2 + 1 < FIN) ? W1[(2 * k2 + 1) * HID + c] : 0.0f;
    __half2 h = __floats2half2_rn(lo, hi);
    Wp[idx] = __builtin_bit_cast(unsigned, h);
}

// Layer-1 GEMM via dot2: 64-row tile, 8 rows x 4 cols per thread.
// X staged fp16 in LDS (read as uint = k-pair half2); W1 packed fp16.
// Epilogue: fp16(dinv*y).
__global__ __launch_bounds__(256) void k_gemm1(const float* __restrict__ X,
                                               const unsigned* __restrict__ W1p,
                                               const float* __restrict__ dinv,
                                               __half* __restrict__ Yh) {
    constexpr int K = FIN;           // 165
    constexpr int KPH = 168;         // half stride per row (84 uints)
    constexpr int KPU = 84;
    __shared__ __half Xs[64 * KPH];
    const int tid = threadIdx.x;
    const long base = (long)blockIdx.x * 64;
    const int rows = (NN - base < 64) ? (int)(NN - base) : 64;

    const float* Xg = X + base * K;
    for (int i = tid; i < rows * K; i += 256) {
        int r = i / K, c = i % K;
        Xs[r * KPH + c] = __float2half(Xg[i]);
    }
    for (int i = tid; i < 64 * 3; i += 256) {        // zero pad c=165..167
        int r = i / 3, c = K + i % 3;
        Xs[r * KPH + c] = __float2half(0.f);
    }
    if (rows < 64) {
        for (int i = tid; i < (64 - rows) * KPH; i += 256)
            Xs[rows * KPH + i] = __float2half(0.f);
    }
    __syncthreads();

    const int cg = tid & 31;
    const int rg = tid >> 5;
    const unsigned* Wp = W1p + 4 * cg;
    const unsigned* XrowU = (const unsigned*)&Xs[rg * 8 * KPH];

    float acc[8][4];
#pragma unroll
    for (int r = 0; r < 8; ++r)
#pragma unroll
        for (int c = 0; c < 4; ++c) acc[r][c] = 0.0f;

    int k2 = 0;
    for (; k2 + 2 <= K2_1; k2 += 2) {               // 41 iters (82 pairs)
        uint4 w0 = *(const uint4*)(Wp + (k2 + 0) * HID);
        uint4 w1 = *(const uint4*)(Wp + (k2 + 1) * HID);
#pragma unroll
        for (int r = 0; r < 8; ++r) {
            uint2 xp = *(const uint2*)&XrowU[r * KPU + k2];   // 8B LDS
            acc[r][0] = fdot2u(xp.x, w0.x, acc[r][0]);
            acc[r][1] = fdot2u(xp.x, w0.y, acc[r][1]);
            acc[r][2] = fdot2u(xp.x, w0.z, acc[r][2]);
            acc[r][3] = fdot2u(xp.x, w0.w, acc[r][3]);
            acc[r][0] = fdot2u(xp.y, w1.x, acc[r][0]);
            acc[r][1] = fdot2u(xp.y, w1.y, acc[r][1]);
            acc[r][2] = fdot2u(xp.y, w1.z, acc[r][2]);
            acc[r][3] = fdot2u(xp.y, w1.w, acc[r][3]);
        }
    }
    {   // leftover pair k2 = 82 (covers k=164 + zero pad)
        uint4 wt = *(const uint4*)(Wp + k2 * HID);
#pragma unroll
        for (int r = 0; r < 8; ++r) {
            unsigned xp = XrowU[r * KPU + k2];
            acc[r][0] = fdot2u(xp, wt.x, acc[r][0]);
            acc[r][1] = fdot2u(xp, wt.y, acc[r][1]);
            acc[r][2] = fdot2u(xp, wt.z, acc[r][2]);
            acc[r][3] = fdot2u(xp, wt.w, acc[r][3]);
        }
    }

#pragma unroll
    for (int r = 0; r < 8; ++r) {
        long row = base + rg * 8 + r;
        if (row < NN) {
            float d = dinv[row];
            __half2 p0 = __floats2half2_rn(acc[r][0] * d, acc[r][1] * d);
            __half2 p1 = __floats2half2_rn(acc[r][2] * d, acc[r][3] * d);
            uint2 uv;
            uv.x = *reinterpret_cast<unsigned int*>(&p0);
            uv.y = *reinterpret_cast<unsigned int*>(&p1);
            *reinterpret_cast<uint2*>(&Yh[row * HID + 4 * cg]) = uv;
        }
    }
}

// Gather sum of pre-scaled fp16 rows (incl. self); lane j owns cols 2j,2j+1.
__device__ __forceinline__ void gather_row_h(const __half2* __restrict__ H2,
                                             const int* __restrict__ rowptr,
                                             const int* __restrict__ col,
                                             int i, int j,
                                             float& a0, float& a1) {
    int k = rowptr[i];
    const int end = rowptr[i + 1];
    float2 self = __half22float2(H2[(size_t)i * 64 + j]);
    a0 = self.x;
    a1 = self.y;
    for (; k + 8 <= end; k += 8) {
        int s[8];
#pragma unroll
        for (int u = 0; u < 8; ++u)
            s[u] = __builtin_nontemporal_load(&col[k + u]);
        __half2 h[8];
#pragma unroll
        for (int u = 0; u < 8; ++u) h[u] = H2[(size_t)s[u] * 64 + j];
#pragma unroll
        for (int u = 0; u < 8; ++u) {
            float2 f = __half22float2(h[u]);
            a0 += f.x;
            a1 += f.y;
        }
    }
    for (; k < end; ++k) {
        int cs = __builtin_nontemporal_load(&col[k]);
        float2 f = __half22float2(H2[(size_t)cs * 64 + j]);
        a0 += f.x;
        a1 += f.y;
    }
}

// Pure gather, wave per 4 nodes.
// MODE 0: out = fp16( di * relu(di*a + b1) );  MODE 1: out = fp16( di * a ).
template<int MODE>
__global__ __launch_bounds__(64) void k_aggP(const __half* __restrict__ Hh,
                                             const int* __restrict__ rowptr,
                                             const int* __restrict__ col,
                                             const float* __restrict__ dinv,
                                             const float* __restrict__ bias,
                                             __half* __restrict__ Oh) {
    const int j = threadIdx.x;
    const int base = blockIdx.x * 4;
    const __half2* H2 = (const __half2*)Hh;
    float2 bb = make_float2(0.f, 0.f);
    if (MODE == 0) bb = ((const float2*)bias)[j];

#pragma unroll
    for (int n = 0; n < 4; ++n) {
        const int i = base + n;
        const float di = dinv[i];
        float a0, a1;
        gather_row_h(H2, rowptr, col, i, j, a0, a1);
        float r0, r1;
        if (MODE == 0) {
            r0 = di * fmaxf(di * a0 + bb.x, 0.0f);
            r1 = di * fmaxf(di * a1 + bb.y, 0.0f);
        } else {
            r0 = di * a0;
            r1 = di * a1;
        }
        ((__half2*)Oh)[(size_t)i * 64 + j] = __floats2half2_rn(r0, r1);
    }
}

// Dense tail: out[i] = relu(u[i] @ W2 + b2) @ W3 + b3, u fp16, dot2 math.
__global__ __launch_bounds__(256) void k_tail(const unsigned* __restrict__ Ug,
                                              const unsigned* __restrict__ W2p,
                                              const float* __restrict__ b2,
                                              const float* __restrict__ W3,
                                              const float* __restrict__ b3,
                                              float* __restrict__ out) {
    __shared__ unsigned Xs[64 * 66];         // [row][k2], stride 66
    __shared__ unsigned Ws[64 * 128];        // [k2][c]
    const int tid = threadIdx.x;
    const long base = (long)blockIdx.x * 64;

#pragma unroll
    for (int i = 0; i < 4; ++i) {
        int li = tid + i * 256;               // uint4 index, 1024 total
        int row = li >> 4;
        int q4  = li & 15;
        uint4 v = make_uint4(0, 0, 0, 0);
        if (base + row < NN)
            v = *(const uint4*)&Ug[(base + row) * 64 + q4 * 4];
        Xs[row * 66 + q4 * 4 + 0] = v.x;
        Xs[row * 66 + q4 * 4 + 1] = v.y;
        Xs[row * 66 + q4 * 4 + 2] = v.z;
        Xs[row * 66 + q4 * 4 + 3] = v.w;
    }
#pragma unroll
    for (int i = 0; i < 8; ++i) {
        int li = tid + i * 256;               // uint4 index, 2048 total
        *(uint4*)&Ws[li * 4] = *(const uint4*)&W2p[li * 4];
    }
    __syncthreads();

    const int cg = tid & 31;
    const int rg = tid >> 5;

    float acc[8][4];
#pragma unroll
    for (int r = 0; r < 8; ++r)
#pragma unroll
        for (int c = 0; c < 4; ++c) acc[r][c] = 0.0f;

    for (int k2 = 0; k2 < 64; k2 += 2) {
        uint4 w0 = *(const uint4*)&Ws[k2 * 128 + 4 * cg];
        uint4 w1 = *(const uint4*)&Ws[(k2 + 1) * 128 + 4 * cg];
#pragma unroll
        for (int r = 0; r < 8; ++r) {
            uint2 xp = *(const uint2*)&Xs[(rg * 8 + r) * 66 + k2];
            acc[r][0] = fdot2u(xp.x, w0.x, acc[r][0]);
            acc[r][1] = fdot2u(xp.x, w0.y, acc[r][1]);
            acc[r][2] = fdot2u(xp.x, w0.z, acc[r][2]);
            acc[r][3] = fdot2u(xp.x, w0.w, acc[r][3]);
            acc[r][0] = fdot2u(xp.y, w1.x, acc[r][0]);
            acc[r][1] = fdot2u(xp.y, w1.y, acc[r][1]);
            acc[r][2] = fdot2u(xp.y, w1.z, acc[r][2]);
            acc[r][3] = fdot2u(xp.y, w1.w, acc[r][3]);
        }
    }

    const float4 bb = *(const float4*)&b2[4 * cg];
    float2 w3v[4];
#pragma unroll
    for (int c = 0; c < 4; ++c)
        w3v[c] = *(const float2*)&W3[(4 * cg + c) * 2];
    const float b30 = b3[0], b31 = b3[1];

#pragma unroll
    for (int r = 0; r < 8; ++r) {
        float h0 = fmaxf(acc[r][0] + bb.x, 0.f);
        float h1 = fmaxf(acc[r][1] + bb.y, 0.f);
        float h2 = fmaxf(acc[r][2] + bb.z, 0.f);
        float h3 = fmaxf(acc[r][3] + bb.w, 0.f);
        float p0 = h0 * w3v[0].x + h1 * w3v[1].x + h2 * w3v[2].x + h3 * w3v[3].x;
        float p1 = h0 * w3v[0].y + h1 * w3v[1].y + h2 * w3v[2].y + h3 * w3v[3].y;
#pragma unroll
        for (int m = 1; m < 32; m <<= 1) {
            p0 += __shfl_xor(p0, m);
            p1 += __shfl_xor(p1, m);
        }
        long row = base + rg * 8 + r;
        if (cg == 0 && row < NN)
            ((float2*)out)[row] = make_float2(p0 + b30, p1 + b31);
    }
}

extern "C" void kernel_launch(void* const* d_in, const int* in_sizes, int n_in,
                              void* d_out, int out_size, void* d_ws, size_t ws_size,
                              hipStream_t stream) {
    const float* x   = (const float*)d_in[0];
    const int*   ei  = (const int*)d_in[1];
    const float* W1  = (const float*)d_in[2];
    const float* b1  = (const float*)d_in[3];
    const float* W2  = (const float*)d_in[4];
    const float* b2  = (const float*)d_in[5];
    const float* W3  = (const float*)d_in[6];
    const float* b3  = (const float*)d_in[7];
    float* out = (float*)d_out;

    const int* srcA = ei;
    const int* dstA = ei + NE;

    char* p = (char*)d_ws;
    auto alloc = [&](size_t bytes) {
        char* r = p;
        p += (bytes + 255) & ~(size_t)255;
        return r;
    };
    float*    dinv   = (float*)alloc(NN * 4);
    int*      counts = (int*)  alloc(NN * 4);        // reused as fill cursor
    int*      rowptr = (int*)  alloc((NN + 1) * 4);
    int*      bsum   = (int*)  alloc(512 * 4);
    int*      col    = (int*)  alloc((size_t)NE * 4);
    unsigned* w2pk   = (unsigned*)alloc(64 * 128 * 4);
    unsigned* w1pk   = (unsigned*)alloc(K2_1 * HID * 4);
    __half*   hhat   = (__half*)alloc((size_t)NN * HID * 2);  // dinv*h1
    __half*   h2hat  = (__half*)alloc((size_t)NN * HID * 2);  // dinv*h2
    __half*   ubuf   = (__half*)alloc((size_t)NN * HID * 2);  // A-hat h2

    const int nb_n = (NN + 255) / 256;
    const int nb_e = (NE + 255) / 256;
    const int nb_g = (NN + 63) / 64;

    // ---- CSR build + weight packs ----
    k_zero_counts<<<nb_n, 256, 0, stream>>>(counts);
    k_hist<<<nb_e, 256, 0, stream>>>(dstA, counts);
    k_w2pack<<<32, 256, 0, stream>>>(W2, w2pk);
    k_w1pack<<<(K2_1 * HID + 255) / 256, 256, 0, stream>>>(W1, w1pk);
    k_scanA<<<nb_n, 256, 0, stream>>>(counts, rowptr, bsum, dinv);
    k_scanB<<<1, 512, 0, stream>>>(bsum, nb_n);
    k_scanC<<<nb_n, 256, 0, stream>>>(rowptr, bsum, counts);
    k_fill_x<<<8 * NCHUNK, 256, 0, stream>>>(srcA, dstA, rowptr, counts, col);

    // ---- layer 1 GEMM (dot2) -> hhat ----
    k_gemm1<<<nb_g, 256, 0, stream>>>(x, w1pk, dinv, hhat);

    // ---- agg1 (pure) -> h2hat ----
    k_aggP<0><<<NN / 4, 64, 0, stream>>>(hhat, rowptr, col, dinv, b1, h2hat);

    // ---- agg2 (pure) -> u ----
    k_aggP<1><<<NN / 4, 64, 0, stream>>>(h2hat, rowptr, col, dinv, nullptr, ubuf);

    // ---- tail: relu(u@W2+b2)@W3+b3 ----
    k_tail<<<nb_g, 256, 0, stream>>>((const unsigned*)ubuf, w2pk, b2, W3, b3, out);
}